// Round 2
// baseline (39099.261 us; speedup 1.0000x reference)
//
#include <hip/hip_runtime.h>
#include <hip/hip_bf16.h>

// GRU: T=512, B=64, Cin=512, H=1024, 2 layers.
// Round 2: persistent per-layer kernel with device-wide barrier replaces the
// 2048 per-step launches. Weights LDS-resident (XOR-swizzled), fp32 master h,
// hi/lo bf16 recurrent operands (same numerics as passing round 1).

#define Hh   1024
#define Bz   64
#define Tt   512
#define Mrows (Tt*Bz)   // 32768
#define NBLK 64

typedef __attribute__((ext_vector_type(8))) short short8;
typedef __attribute__((ext_vector_type(4))) float f32x4;

__device__ __forceinline__ unsigned short f2bf(float f){
  unsigned u = __builtin_bit_cast(unsigned, f);
  u += 0x7fffu + ((u >> 16) & 1u);          // round-to-nearest-even
  return (unsigned short)(u >> 16);
}
__device__ __forceinline__ float bf2f(unsigned short s){
  unsigned u = ((unsigned)s) << 16;
  return __builtin_bit_cast(float, u);
}

__device__ __forceinline__ void gload16(const void* g, void* l){
  __builtin_amdgcn_global_load_lds(
      (const __attribute__((address_space(1))) unsigned int*)g,
      (__attribute__((address_space(3))) unsigned int*)l, 16, 0, 0);
}

// device-wide sense barrier: bar[0]=count, bar[1]=generation
__device__ __forceinline__ void gbar(unsigned* bar){
  __syncthreads();
  if (threadIdx.x == 0){
    __threadfence();   // release: drain my writes to the coherence point
    unsigned g = __hip_atomic_load(&bar[1], __ATOMIC_RELAXED, __HIP_MEMORY_SCOPE_AGENT);
    unsigned a = __hip_atomic_fetch_add(&bar[0], 1u, __ATOMIC_ACQ_REL, __HIP_MEMORY_SCOPE_AGENT);
    if (a == NBLK - 1u){
      __hip_atomic_store(&bar[0], 0u,   __ATOMIC_RELAXED, __HIP_MEMORY_SCOPE_AGENT);
      __hip_atomic_store(&bar[1], g+1u, __ATOMIC_RELEASE, __HIP_MEMORY_SCOPE_AGENT);
    } else {
      while (__hip_atomic_load(&bar[1], __ATOMIC_RELAXED, __HIP_MEMORY_SCOPE_AGENT) == g)
        __builtin_amdgcn_s_sleep(2);
    }
    __threadfence();   // acquire: invalidate L1/L2 so fresh data is visible
  }
  __syncthreads();
}

// ---------------- prep kernels ----------------

__global__ __launch_bounds__(256) void k_cvt_bf16(const float* __restrict__ src,
                                                  unsigned short* __restrict__ dst, int n4){
  int i = blockIdx.x*blockDim.x + threadIdx.x;
  int stride = gridDim.x*blockDim.x;
  for (; i < n4; i += stride){
    float4 v = reinterpret_cast<const float4*>(src)[i];
    ushort4 o; o.x=f2bf(v.x); o.y=f2bf(v.y); o.z=f2bf(v.z); o.w=f2bf(v.w);
    reinterpret_cast<ushort4*>(dst)[i] = o;
  }
}

// fp32 (K,N) -> bf16 (N,K), 64x64 LDS tile
__global__ __launch_bounds__(256) void k_transpose_bf16(const float* __restrict__ src,
                                                        unsigned short* __restrict__ dst,
                                                        int K, int N){
  __shared__ float tile[64][65];
  int k0 = blockIdx.x * 64, n0 = blockIdx.y * 64;
  int t = threadIdx.x;
  int r = t >> 4, c4 = (t & 15) << 2;
  #pragma unroll
  for (int j = 0; j < 4; ++j){
    const float4 v = *reinterpret_cast<const float4*>(&src[(size_t)(k0 + r + j*16) * N + n0 + c4]);
    tile[r+j*16][c4+0]=v.x; tile[r+j*16][c4+1]=v.y;
    tile[r+j*16][c4+2]=v.z; tile[r+j*16][c4+3]=v.w;
  }
  __syncthreads();
  #pragma unroll
  for (int j = 0; j < 4; ++j){
    int nn = r + j*16;
    ushort4 o;
    o.x = f2bf(tile[c4+0][nn]); o.y = f2bf(tile[c4+1][nn]);
    o.z = f2bf(tile[c4+2][nn]); o.w = f2bf(tile[c4+3][nn]);
    *reinterpret_cast<ushort4*>(&dst[(size_t)(n0+nn)*K + k0 + c4]) = o;
  }
}

__global__ void k_bias_fold(const float* __restrict__ a, const float* __restrict__ b,
                            const float* __restrict__ c, const float* __restrict__ d,
                            float* __restrict__ out){
  int i = blockIdx.x*blockDim.x + threadIdx.x;
  if (i < 2048) out[i] = a[i] + b[i];
  else if (i < 3072) out[i] = c[i-2048] + d[i-2048];
}

// ---------------- big x-projection GEMM ----------------
__global__ __launch_bounds__(256) void k_xproj_gemm(
    const unsigned short* __restrict__ A, const unsigned short* __restrict__ Bt,
    const float* __restrict__ bias, unsigned short* __restrict__ outRZ,
    float* __restrict__ outC, int K)
{
  __shared__ __align__(16) unsigned short As[128*32];
  __shared__ __align__(16) unsigned short Bs[128*32];
  const int nb = blockIdx.x, mb = blockIdx.y;
  const int m0 = mb*128, n0 = nb*128;
  const int t = threadIdx.x, lane = t & 63, w = t >> 6;
  const int wr = w >> 1, wc = w & 1;
  const int lr = lane & 15, lq = lane >> 4;
  const int sr = t >> 2, scg = t & 3;
  f32x4 acc[4][4];
  const f32x4 zero4 = {0.f,0.f,0.f,0.f};
  #pragma unroll
  for (int mt=0;mt<4;++mt)
    #pragma unroll
    for (int nt=0;nt<4;++nt) acc[mt][nt] = zero4;

  const unsigned short* ga0 = &A [(size_t)(m0 + sr     )*K + scg*8];
  const unsigned short* ga1 = &A [(size_t)(m0 + sr + 64)*K + scg*8];
  const unsigned short* gb0 = &Bt[(size_t)(n0 + sr     )*K + scg*8];
  const unsigned short* gb1 = &Bt[(size_t)(n0 + sr + 64)*K + scg*8];
  char* lA = (char*)As + w*1024;
  char* lB = (char*)Bs + w*1024;
  const int kiters = K >> 5;
  for (int kt = 0; kt < kiters; ++kt){
    __syncthreads();
    gload16(ga0 + kt*32, lA);
    gload16(ga1 + kt*32, lA + 4096);
    gload16(gb0 + kt*32, lB);
    gload16(gb1 + kt*32, lB + 4096);
    asm volatile("s_waitcnt vmcnt(0)" ::: "memory");
    __syncthreads();
    short8 af[4], bfr[4];
    #pragma unroll
    for (int mt=0; mt<4; ++mt)
      af[mt] = *reinterpret_cast<const short8*>(&As[(wr*64 + mt*16 + lr)*32 + lq*8]);
    #pragma unroll
    for (int nt=0; nt<4; ++nt)
      bfr[nt] = *reinterpret_cast<const short8*>(&Bs[(wc*64 + nt*16 + lr)*32 + lq*8]);
    #pragma unroll
    for (int mt=0; mt<4; ++mt)
      #pragma unroll
      for (int nt=0; nt<4; ++nt)
        acc[mt][nt] = __builtin_amdgcn_mfma_f32_16x16x32_bf16(af[mt], bfr[nt], acc[mt][nt], 0,0,0);
  }
  const bool isRZ = (n0 < 2048);
  #pragma unroll
  for (int mt=0;mt<4;++mt){
    #pragma unroll
    for (int nt=0;nt<4;++nt){
      int gn = n0 + wc*64 + nt*16 + lr;
      float bv = bias[gn];
      #pragma unroll
      for (int i=0;i<4;++i){
        int gm = m0 + wr*64 + mt*16 + lq*4 + i;
        float v = acc[mt][nt][i] + bv;
        if (isRZ) outRZ[(size_t)gm*2048 + gn] = f2bf(v);
        else      outC [(size_t)gm*1024 + (gn - 2048)] = v;
      }
    }
  }
}

// ---------------- persistent per-layer recurrent kernel ----------------
// 64 blocks x 512 threads. Block b:
//   phase A: rz cols [32b,32b+32)  (b<32 -> r-cols, b>=32 -> z-cols)
//   phase B: cand cols [16b,16b+16), K split across wave-halves
__global__ __launch_bounds__(512) void k_gru_layer(
    const unsigned short* __restrict__ Wrzg,   // (2048,1024) bf16
    const unsigned short* __restrict__ Whhg,   // (1024,1024) bf16
    const unsigned short* __restrict__ XprojRZ,// (T,64,2048) bf16, biases folded
    const float* __restrict__ XprojC,          // (T,64,1024) fp32, biases folded
    float* __restrict__ hfp, unsigned short* __restrict__ hhi, unsigned short* __restrict__ hlo,
    unsigned short* __restrict__ abhi, unsigned short* __restrict__ ablo,
    float* __restrict__ zbuf,
    unsigned short* __restrict__ h0seq,        // L0: bf16 sequence out (else null)
    float* __restrict__ outseq,                // L1: fp32 sequence out (else null)
    float* __restrict__ hn,                    // final h slot
    unsigned* __restrict__ bar)
{
  __shared__ __align__(16) unsigned short WrzS[32*1024];  // 64KB, XOR-swizzled rows
  __shared__ __align__(16) unsigned short WhhS[16*1024];  // 32KB
  __shared__ float partial[4][64][4];                     // 4KB, phase-B k-combine

  const int b   = blockIdx.x;
  const int tid = threadIdx.x;
  const int lane = tid & 63, w = tid >> 6;
  const int lr = lane & 15, lq = lane >> 4;

  // ---- stage weights into LDS (once), XOR-swizzle rows (T2) ----
  #pragma unroll
  for (int j = 0; j < 8; ++j){
    int lin = (tid + j*512) * 8;
    int n = lin >> 10, k = lin & 1023;
    short8 v = *reinterpret_cast<const short8*>(&Wrzg[(size_t)(32*b + n)*1024 + k]);
    *reinterpret_cast<short8*>(&WrzS[(n*1024 + k) ^ ((n&7)<<3)]) = v;
  }
  #pragma unroll
  for (int j = 0; j < 4; ++j){
    int lin = (tid + j*512) * 8;
    int n = lin >> 10, k = lin & 1023;
    short8 v = *reinterpret_cast<const short8*>(&Whhg[(size_t)(16*b + n)*1024 + k]);
    *reinterpret_cast<short8*>(&WhhS[(n*1024 + k) ^ ((n&7)<<3)]) = v;
  }
  // ---- zero my h slice (cols [16b,16b+16)) ----
  #pragma unroll
  for (int j = 0; j < 2; ++j){
    int idx = tid + j*512;
    int r = idx >> 4, c = 16*b + (idx & 15);
    hfp[r*1024+c] = 0.f; hhi[r*1024+c] = 0; hlo[r*1024+c] = 0;
  }
  gbar(bar);

  const int mw = w >> 1, nw = w & 1;      // phase A: wave = (m-tile, n-half)
  const int rowA = 16*mw;
  const int colA = 32*b + 16*nw;          // global rz col base
  const int nloc = 16*nw + lr;            // local Wrz row
  const bool isR = (b < 32);
  const int mwB = w & 3, kg = w >> 2;     // phase B: wave = (m-tile, k-half)
  const int colB = 16*b;

  for (int t = 0; t < Tt; ++t){
    // ================= phase A: rz preact + gates =================
    {
      const unsigned short* xprz_t = XprojRZ + (size_t)t*Bz*2048;
      const unsigned short* hh = hhi + (rowA + lr)*1024;
      const unsigned short* hl = hlo + (rowA + lr)*1024;
      // hoist epilogue loads (hide latency under MFMA loop)
      unsigned short xv[4]; float hv[4];
      #pragma unroll
      for (int i = 0; i < 4; ++i)
        xv[i] = xprz_t[(rowA + lq*4 + i)*2048 + colA + lr];
      if (isR){
        #pragma unroll
        for (int i = 0; i < 4; ++i)
          hv[i] = hfp[(rowA + lq*4 + i)*1024 + colA + lr];
      }
      f32x4 acc = {0.f,0.f,0.f,0.f};
      #pragma unroll 8
      for (int ks = 0; ks < 32; ++ks){
        int kl = ks*32 + lq*8;
        short8 ah = *reinterpret_cast<const short8*>(hh + kl);
        short8 al = *reinterpret_cast<const short8*>(hl + kl);
        short8 bb = *reinterpret_cast<const short8*>(&WrzS[(nloc*1024 + kl) ^ ((nloc&7)<<3)]);
        acc = __builtin_amdgcn_mfma_f32_16x16x32_bf16(ah, bb, acc, 0,0,0);
        acc = __builtin_amdgcn_mfma_f32_16x16x32_bf16(al, bb, acc, 0,0,0);
      }
      #pragma unroll
      for (int i = 0; i < 4; ++i){
        int row = rowA + lq*4 + i;
        int col = colA + lr;
        float pre = acc[i] + bf2f(xv[i]);
        float s = 1.f / (1.f + __expf(-pre));
        if (isR){
          float av = hv[i] * s;
          unsigned short hi = f2bf(av);
          abhi[row*1024+col] = hi;
          ablo[row*1024+col] = f2bf(av - bf2f(hi));
        } else {
          zbuf[row*1024 + col - 1024] = s;
        }
      }
    }
    gbar(bar);
    // ================= phase B: cand + state update =================
    {
      const unsigned short* ah_ = abhi + (16*mwB + lr)*1024 + kg*512;
      const unsigned short* al_ = ablo + (16*mwB + lr)*1024 + kg*512;
      const float* xc_t = XprojC + (size_t)t*Bz*1024;
      float xcv[4], zv[4], hv[4];
      if (kg == 0){
        #pragma unroll
        for (int i = 0; i < 4; ++i){
          int row = 16*mwB + lq*4 + i, col = colB + lr;
          xcv[i] = xc_t[row*1024 + col];
          zv[i]  = zbuf[row*1024 + col];
          hv[i]  = hfp [row*1024 + col];
        }
      }
      f32x4 acc = {0.f,0.f,0.f,0.f};
      #pragma unroll 8
      for (int ks = 0; ks < 16; ++ks){
        int kl = ks*32 + lq*8;
        int kw = kg*512 + kl;
        short8 ah = *reinterpret_cast<const short8*>(ah_ + kl);
        short8 al = *reinterpret_cast<const short8*>(al_ + kl);
        short8 bb = *reinterpret_cast<const short8*>(&WhhS[(lr*1024 + kw) ^ ((lr&7)<<3)]);
        acc = __builtin_amdgcn_mfma_f32_16x16x32_bf16(ah, bb, acc, 0,0,0);
        acc = __builtin_amdgcn_mfma_f32_16x16x32_bf16(al, bb, acc, 0,0,0);
      }
      if (kg == 1){
        #pragma unroll
        for (int i = 0; i < 4; ++i) partial[mwB][lane][i] = acc[i];
      }
      __syncthreads();
      if (kg == 0){
        #pragma unroll
        for (int i = 0; i < 4; ++i){
          int row = 16*mwB + lq*4 + i;
          int col = colB + lr;
          float pre = acc[i] + partial[mwB][lane][i] + xcv[i];
          float cand = tanhf(pre);
          float hnew = zv[i]*hv[i] + (1.f - zv[i])*cand;
          hfp[row*1024+col] = hnew;
          unsigned short hi = f2bf(hnew);
          hhi[row*1024+col] = hi;
          hlo[row*1024+col] = f2bf(hnew - bf2f(hi));
          if (h0seq)  h0seq [(size_t)t*(Bz*Hh) + row*1024 + col] = hi;
          if (outseq) outseq[(size_t)t*(Bz*Hh) + row*1024 + col] = hnew;
          if (t == Tt-1) hn[row*1024 + col] = hnew;
        }
      }
    }
    gbar(bar);
  }
}

// ---------------- host ----------------

extern "C" void kernel_launch(void* const* d_in, const int* in_sizes, int n_in,
                              void* d_out, int out_size, void* d_ws, size_t ws_size,
                              hipStream_t stream)
{
  (void)in_sizes; (void)n_in; (void)out_size; (void)ws_size;
  const float* X     = (const float*)d_in[0];
  const float* Wxrz0 = (const float*)d_in[1];
  const float* bxrz0 = (const float*)d_in[2];
  const float* Whrz0 = (const float*)d_in[3];
  const float* bhrz0 = (const float*)d_in[4];
  const float* Wxh0  = (const float*)d_in[5];
  const float* bxh0  = (const float*)d_in[6];
  const float* Whh0  = (const float*)d_in[7];
  const float* bhh0  = (const float*)d_in[8];
  const float* Wxrz1 = (const float*)d_in[9];
  const float* bxrz1 = (const float*)d_in[10];
  const float* Whrz1 = (const float*)d_in[11];
  const float* bhrz1 = (const float*)d_in[12];
  const float* Wxh1  = (const float*)d_in[13];
  const float* bxh1  = (const float*)d_in[14];
  const float* Whh1  = (const float*)d_in[15];
  const float* bhh1  = (const float*)d_in[16];

  char* p = (char*)d_ws;
  auto carve = [&](size_t bytes)->char*{
    char* r = p; p += (bytes + 255) & ~(size_t)255; return r;
  };
  unsigned short* Xbf    = (unsigned short*)carve((size_t)Mrows*512*2);
  unsigned short* W0t    = (unsigned short*)carve((size_t)3072*512*2);
  unsigned short* W1t    = (unsigned short*)carve((size_t)3072*1024*2);
  unsigned short* Whrz0t = (unsigned short*)carve((size_t)2048*1024*2);
  unsigned short* Whh0t  = (unsigned short*)carve((size_t)1024*1024*2);
  unsigned short* Whrz1t = (unsigned short*)carve((size_t)2048*1024*2);
  unsigned short* Whh1t  = (unsigned short*)carve((size_t)1024*1024*2);
  float* bias0 = (float*)carve(3072*4);
  float* bias1 = (float*)carve(3072*4);
  unsigned short* XprojRZ = (unsigned short*)carve((size_t)Mrows*2048*2);
  float*          XprojC  = (float*)carve((size_t)Mrows*1024*4);
  unsigned short* H0seq   = (unsigned short*)carve((size_t)Mrows*1024*2);
  float* hfp = (float*)carve(Bz*Hh*4);
  unsigned short* hhi  = (unsigned short*)carve(Bz*Hh*2);
  unsigned short* hlo  = (unsigned short*)carve(Bz*Hh*2);
  unsigned short* abhi = (unsigned short*)carve(Bz*Hh*2);
  unsigned short* ablo = (unsigned short*)carve(Bz*Hh*2);
  float* zbuf = (float*)carve(Bz*Hh*4);
  unsigned* bar = (unsigned*)carve(256);

  hipMemsetAsync(bar, 0, 256, stream);

  k_cvt_bf16<<<2048,256,0,stream>>>(X, Xbf, Mrows*512/4);
  k_transpose_bf16<<<dim3(8,32), 256,0,stream>>>(Wxrz0, W0t, 512, 2048);
  k_transpose_bf16<<<dim3(8,16), 256,0,stream>>>(Wxh0,  W0t + (size_t)2048*512, 512, 1024);
  k_transpose_bf16<<<dim3(16,32),256,0,stream>>>(Whrz0, Whrz0t, 1024, 2048);
  k_transpose_bf16<<<dim3(16,16),256,0,stream>>>(Whh0,  Whh0t, 1024, 1024);
  k_transpose_bf16<<<dim3(16,32),256,0,stream>>>(Wxrz1, W1t, 1024, 2048);
  k_transpose_bf16<<<dim3(16,16),256,0,stream>>>(Wxh1,  W1t + (size_t)2048*1024, 1024, 1024);
  k_transpose_bf16<<<dim3(16,32),256,0,stream>>>(Whrz1, Whrz1t, 1024, 2048);
  k_transpose_bf16<<<dim3(16,16),256,0,stream>>>(Whh1,  Whh1t, 1024, 1024);
  k_bias_fold<<<12,256,0,stream>>>(bxrz0, bhrz0, bxh0, bhh0, bias0);
  k_bias_fold<<<12,256,0,stream>>>(bxrz1, bhrz1, bxh1, bhh1, bias1);

  float* out = (float*)d_out;
  float* hn0 = out + (size_t)Mrows*Hh;
  float* hn1 = hn0 + Bz*Hh;

  // ---- layer 0 ----
  k_xproj_gemm<<<dim3(24,256),256,0,stream>>>(Xbf, W0t, bias0, XprojRZ, XprojC, 512);
  k_gru_layer<<<NBLK,512,0,stream>>>(Whrz0t, Whh0t, XprojRZ, XprojC,
                                     hfp, hhi, hlo, abhi, ablo, zbuf,
                                     H0seq, nullptr, hn0, bar);
  // ---- layer 1 ----
  k_xproj_gemm<<<dim3(24,256),256,0,stream>>>(H0seq, W1t, bias1, XprojRZ, XprojC, 1024);
  k_gru_layer<<<NBLK,512,0,stream>>>(Whrz1t, Whh1t, XprojRZ, XprojC,
                                     hfp, hhi, hlo, abhi, ablo, zbuf,
                                     nullptr, out, hn1, bar);
}

// Round 3
// 38579.721 us; speedup vs baseline: 1.0135x; 1.0135x over previous
//
#include <hip/hip_runtime.h>
#include <hip/hip_bf16.h>

// GRU: T=512, B=64, Cin=512, H=1024, 2 layers.
// Round 3: fence-FREE persistent kernel. All cross-block state goes through
// relaxed agent-scope atomics (L2-bypass, coherent at L3) so the global
// barrier needs no buffer_wbl2/buffer_inv L2 flushes (round 2's 16us/barrier).

#define Hh   1024
#define Bz   64
#define Tt   512
#define Mrows (Tt*Bz)   // 32768
#define NBLK 64

typedef __attribute__((ext_vector_type(8))) short short8;
typedef __attribute__((ext_vector_type(4))) float f32x4;
typedef unsigned long long u64;

__device__ __forceinline__ unsigned short f2bf(float f){
  unsigned u = __builtin_bit_cast(unsigned, f);
  u += 0x7fffu + ((u >> 16) & 1u);          // round-to-nearest-even
  return (unsigned short)(u >> 16);
}
__device__ __forceinline__ float bf2f(unsigned short s){
  unsigned u = ((unsigned)s) << 16;
  return __builtin_bit_cast(float, u);
}

// ---- coherent (agent-scope, relaxed) access helpers: bypass stale L2 ----
__device__ __forceinline__ u64 cload_u64(const void* p){
  return __hip_atomic_load((const u64*)p, __ATOMIC_RELAXED, __HIP_MEMORY_SCOPE_AGENT);
}
__device__ __forceinline__ float cload_f32(const float* p){
  return __hip_atomic_load(p, __ATOMIC_RELAXED, __HIP_MEMORY_SCOPE_AGENT);
}
__device__ __forceinline__ void cstore_u32(void* p, unsigned v){
  __hip_atomic_store((unsigned*)p, v, __ATOMIC_RELAXED, __HIP_MEMORY_SCOPE_AGENT);
}
__device__ __forceinline__ void cstore_f32(float* p, float v){
  __hip_atomic_store(p, v, __ATOMIC_RELAXED, __HIP_MEMORY_SCOPE_AGENT);
}
// 16B MFMA fragment via two coherent u64 loads (16B-aligned p)
__device__ __forceinline__ short8 cfrag(const unsigned short* p){
  union { u64 q[2]; short8 v; } u;
  u.q[0] = cload_u64(p);
  u.q[1] = cload_u64(p + 4);
  return u.v;
}

__device__ __forceinline__ void gload16(const void* g, void* l){
  __builtin_amdgcn_global_load_lds(
      (const __attribute__((address_space(1))) unsigned int*)g,
      (__attribute__((address_space(3))) unsigned int*)l, 16, 0, 0);
}

// fence-free device barrier: monotonic counter, no reset, no cache flushes.
__device__ __forceinline__ void gbar(unsigned* bar, unsigned* bk){
  __syncthreads();
  *bk += 1;
  if (threadIdx.x == 0){
    asm volatile("s_waitcnt vmcnt(0)" ::: "memory");  // my coherent stores done
    __hip_atomic_fetch_add(bar, 1u, __ATOMIC_RELAXED, __HIP_MEMORY_SCOPE_AGENT);
    const unsigned tgt = (*bk) * NBLK;
    while (__hip_atomic_load(bar, __ATOMIC_RELAXED, __HIP_MEMORY_SCOPE_AGENT) < tgt) {}
  }
  __syncthreads();
}

// ---------------- prep kernels ----------------

__global__ __launch_bounds__(256) void k_cvt_bf16(const float* __restrict__ src,
                                                  unsigned short* __restrict__ dst, int n4){
  int i = blockIdx.x*blockDim.x + threadIdx.x;
  int stride = gridDim.x*blockDim.x;
  for (; i < n4; i += stride){
    float4 v = reinterpret_cast<const float4*>(src)[i];
    ushort4 o; o.x=f2bf(v.x); o.y=f2bf(v.y); o.z=f2bf(v.z); o.w=f2bf(v.w);
    reinterpret_cast<ushort4*>(dst)[i] = o;
  }
}

// fp32 (K,N) -> bf16 (N,K), 64x64 LDS tile
__global__ __launch_bounds__(256) void k_transpose_bf16(const float* __restrict__ src,
                                                        unsigned short* __restrict__ dst,
                                                        int K, int N){
  __shared__ float tile[64][65];
  int k0 = blockIdx.x * 64, n0 = blockIdx.y * 64;
  int t = threadIdx.x;
  int r = t >> 4, c4 = (t & 15) << 2;
  #pragma unroll
  for (int j = 0; j < 4; ++j){
    const float4 v = *reinterpret_cast<const float4*>(&src[(size_t)(k0 + r + j*16) * N + n0 + c4]);
    tile[r+j*16][c4+0]=v.x; tile[r+j*16][c4+1]=v.y;
    tile[r+j*16][c4+2]=v.z; tile[r+j*16][c4+3]=v.w;
  }
  __syncthreads();
  #pragma unroll
  for (int j = 0; j < 4; ++j){
    int nn = r + j*16;
    ushort4 o;
    o.x = f2bf(tile[c4+0][nn]); o.y = f2bf(tile[c4+1][nn]);
    o.z = f2bf(tile[c4+2][nn]); o.w = f2bf(tile[c4+3][nn]);
    *reinterpret_cast<ushort4*>(&dst[(size_t)(n0+nn)*K + k0 + c4]) = o;
  }
}

__global__ void k_bias_fold(const float* __restrict__ a, const float* __restrict__ b,
                            const float* __restrict__ c, const float* __restrict__ d,
                            float* __restrict__ out){
  int i = blockIdx.x*blockDim.x + threadIdx.x;
  if (i < 2048) out[i] = a[i] + b[i];
  else if (i < 3072) out[i] = c[i-2048] + d[i-2048];
}

// ---------------- big x-projection GEMM ----------------
__global__ __launch_bounds__(256) void k_xproj_gemm(
    const unsigned short* __restrict__ A, const unsigned short* __restrict__ Bt,
    const float* __restrict__ bias, unsigned short* __restrict__ outRZ,
    float* __restrict__ outC, int K)
{
  __shared__ __align__(16) unsigned short As[128*32];
  __shared__ __align__(16) unsigned short Bs[128*32];
  const int nb = blockIdx.x, mb = blockIdx.y;
  const int m0 = mb*128, n0 = nb*128;
  const int t = threadIdx.x, lane = t & 63, w = t >> 6;
  const int wr = w >> 1, wc = w & 1;
  const int lr = lane & 15, lq = lane >> 4;
  const int sr = t >> 2, scg = t & 3;
  f32x4 acc[4][4];
  const f32x4 zero4 = {0.f,0.f,0.f,0.f};
  #pragma unroll
  for (int mt=0;mt<4;++mt)
    #pragma unroll
    for (int nt=0;nt<4;++nt) acc[mt][nt] = zero4;

  const unsigned short* ga0 = &A [(size_t)(m0 + sr     )*K + scg*8];
  const unsigned short* ga1 = &A [(size_t)(m0 + sr + 64)*K + scg*8];
  const unsigned short* gb0 = &Bt[(size_t)(n0 + sr     )*K + scg*8];
  const unsigned short* gb1 = &Bt[(size_t)(n0 + sr + 64)*K + scg*8];
  char* lA = (char*)As + w*1024;
  char* lB = (char*)Bs + w*1024;
  const int kiters = K >> 5;
  for (int kt = 0; kt < kiters; ++kt){
    __syncthreads();
    gload16(ga0 + kt*32, lA);
    gload16(ga1 + kt*32, lA + 4096);
    gload16(gb0 + kt*32, lB);
    gload16(gb1 + kt*32, lB + 4096);
    asm volatile("s_waitcnt vmcnt(0)" ::: "memory");
    __syncthreads();
    short8 af[4], bfr[4];
    #pragma unroll
    for (int mt=0; mt<4; ++mt)
      af[mt] = *reinterpret_cast<const short8*>(&As[(wr*64 + mt*16 + lr)*32 + lq*8]);
    #pragma unroll
    for (int nt=0; nt<4; ++nt)
      bfr[nt] = *reinterpret_cast<const short8*>(&Bs[(wc*64 + nt*16 + lr)*32 + lq*8]);
    #pragma unroll
    for (int mt=0; mt<4; ++mt)
      #pragma unroll
      for (int nt=0; nt<4; ++nt)
        acc[mt][nt] = __builtin_amdgcn_mfma_f32_16x16x32_bf16(af[mt], bfr[nt], acc[mt][nt], 0,0,0);
  }
  const bool isRZ = (n0 < 2048);
  #pragma unroll
  for (int mt=0;mt<4;++mt){
    #pragma unroll
    for (int nt=0;nt<4;++nt){
      int gn = n0 + wc*64 + nt*16 + lr;
      float bv = bias[gn];
      #pragma unroll
      for (int i=0;i<4;++i){
        int gm = m0 + wr*64 + mt*16 + lq*4 + i;
        float v = acc[mt][nt][i] + bv;
        if (isRZ) outRZ[(size_t)gm*2048 + gn] = f2bf(v);
        else      outC [(size_t)gm*1024 + (gn - 2048)] = v;
      }
    }
  }
}

// ---------------- persistent per-layer recurrent kernel ----------------
// 64 blocks x 512 threads (1 block/CU). Block b:
//   phase A: rz cols [32b,32b+32)  (b<32 -> r-cols, b>=32 -> z-cols), waves 0-3
//   phase B: cand cols [16b,16b+16), waves (m-tile 0-3) x (k-half 0-1)
__global__ __launch_bounds__(512) void k_gru_layer(
    const unsigned short* __restrict__ Wrzg,   // (2048,1024) bf16
    const unsigned short* __restrict__ Whhg,   // (1024,1024) bf16
    const unsigned short* __restrict__ XprojRZ,// (T,64,2048) bf16, biases folded
    const float* __restrict__ XprojC,          // (T,64,1024) fp32, biases folded
    float* hfp, unsigned short* hhi, unsigned short* hlo,
    unsigned short* abhi, unsigned short* ablo,
    float* zbuf,
    unsigned short* __restrict__ h0seq,        // L0: bf16 sequence out (else null)
    float* __restrict__ outseq,                // L1: fp32 sequence out (else null)
    float* __restrict__ hn,                    // final h slot
    unsigned* bar)
{
  __shared__ __align__(16) unsigned short WrzS[32*1024];  // 64KB
  __shared__ __align__(16) unsigned short WhhS[16*1024];  // 32KB
  __shared__ float partial[4][64][5];                     // stride-5: no bank conflict

  const int b   = blockIdx.x;
  const int tid = threadIdx.x;
  const int lane = tid & 63, w = tid >> 6;
  const int lr = lane & 15, lq = lane >> 4;
  unsigned bk = 0;

  // ---- stage weights into LDS (once), XOR-swizzled rows ----
  #pragma unroll
  for (int j = 0; j < 8; ++j){
    int lin = (tid + j*512) * 8;
    int n = lin >> 10, k = lin & 1023;
    short8 v = *reinterpret_cast<const short8*>(&Wrzg[(size_t)(32*b + n)*1024 + k]);
    *reinterpret_cast<short8*>(&WrzS[(n*1024 + k) ^ ((n&7)<<3)]) = v;
  }
  #pragma unroll
  for (int j = 0; j < 4; ++j){
    int lin = (tid + j*512) * 8;
    int n = lin >> 10, k = lin & 1023;
    short8 v = *reinterpret_cast<const short8*>(&Whhg[(size_t)(16*b + n)*1024 + k]);
    *reinterpret_cast<short8*>(&WhhS[(n*1024 + k) ^ ((n&7)<<3)]) = v;
  }
  // ---- zero my h slice cols [16b,16b+16) with COHERENT stores (ws poisoned) ----
  {
    int r = tid >> 3, cp = (tid & 7) * 2;
    cstore_u32(&hhi[r*1024 + 16*b + cp], 0u);
    cstore_u32(&hlo[r*1024 + 16*b + cp], 0u);
    int r2 = tid >> 4, c2 = 16*b + (tid & 15);
    cstore_f32(&hfp[r2*1024 + c2], 0.f);
    cstore_f32(&hfp[(r2+32)*1024 + c2], 0.f);
  }
  gbar(bar, &bk);

  const bool isR = (b < 32);
  const int mwB = w & 3, kg = w >> 2;     // phase B decomposition
  const int colB = 16*b;

  for (int t = 0; t < Tt; ++t){
    // ================= phase A: rz preact + gates (waves 0-3) =================
    if (w < 4){
      const int rowA = 16*w;
      const unsigned short* xprz_t = XprojRZ + (size_t)t*Bz*2048;
      const unsigned short* hh = hhi + (rowA + lr)*1024;
      const unsigned short* hl = hlo + (rowA + lr)*1024;
      // hoist epilogue loads
      unsigned short xv[2][4]; float hv[2][4];
      #pragma unroll
      for (int nh = 0; nh < 2; ++nh){
        int col = 32*b + 16*nh + lr;
        #pragma unroll
        for (int i = 0; i < 4; ++i)
          xv[nh][i] = xprz_t[(rowA + lq*4 + i)*2048 + col];
        if (isR){
          #pragma unroll
          for (int i = 0; i < 4; ++i)
            hv[nh][i] = cload_f32(&hfp[(rowA + lq*4 + i)*1024 + col]);
        }
      }
      f32x4 acc0 = {0.f,0.f,0.f,0.f}, acc1 = {0.f,0.f,0.f,0.f};
      #pragma unroll 4
      for (int ks = 0; ks < 32; ++ks){
        int kl = ks*32 + lq*8;
        short8 ah = cfrag(hh + kl);
        short8 al = cfrag(hl + kl);
        short8 b0 = *reinterpret_cast<const short8*>(&WrzS[(lr*1024 + kl) ^ ((lr&7)<<3)]);
        short8 b1 = *reinterpret_cast<const short8*>(&WrzS[((16+lr)*1024 + kl) ^ ((lr&7)<<3)]);
        acc0 = __builtin_amdgcn_mfma_f32_16x16x32_bf16(ah, b0, acc0, 0,0,0);
        acc0 = __builtin_amdgcn_mfma_f32_16x16x32_bf16(al, b0, acc0, 0,0,0);
        acc1 = __builtin_amdgcn_mfma_f32_16x16x32_bf16(ah, b1, acc1, 0,0,0);
        acc1 = __builtin_amdgcn_mfma_f32_16x16x32_bf16(al, b1, acc1, 0,0,0);
      }
      #pragma unroll
      for (int nh = 0; nh < 2; ++nh){
        const f32x4 acc = nh ? acc1 : acc0;
        #pragma unroll
        for (int i = 0; i < 4; ++i){
          int row = rowA + lq*4 + i;
          int col = 32*b + 16*nh + lr;
          float pre = acc[i] + bf2f(xv[nh][i]);
          float s = 1.f / (1.f + __expf(-pre));
          if (isR){
            float av = hv[nh][i] * s;
            unsigned short hi = f2bf(av);
            unsigned short lo = f2bf(av - bf2f(hi));
            unsigned hi2 = (unsigned)__shfl_down((int)hi, 1) & 0xffffu;
            unsigned lo2 = (unsigned)__shfl_down((int)lo, 1) & 0xffffu;
            if (!(lane & 1)){
              cstore_u32(&abhi[row*1024+col], (unsigned)hi | (hi2<<16));
              cstore_u32(&ablo[row*1024+col], (unsigned)lo | (lo2<<16));
            }
          } else {
            cstore_f32(&zbuf[row*1024 + col - 1024], s);
          }
        }
      }
    }
    gbar(bar, &bk);
    // ================= phase B: cand + state update =================
    {
      const unsigned short* ah_ = abhi + (16*mwB + lr)*1024 + kg*512;
      const unsigned short* al_ = ablo + (16*mwB + lr)*1024 + kg*512;
      const float* xc_t = XprojC + (size_t)t*Bz*1024;
      float xcv[4], zv[4], hv[4];
      if (kg == 0){
        #pragma unroll
        for (int i = 0; i < 4; ++i){
          int row = 16*mwB + lq*4 + i, col = colB + lr;
          xcv[i] = xc_t[row*1024 + col];
          zv[i]  = cload_f32(&zbuf[row*1024 + col]);
          hv[i]  = cload_f32(&hfp [row*1024 + col]);
        }
      }
      f32x4 acc = {0.f,0.f,0.f,0.f};
      #pragma unroll 4
      for (int ks = 0; ks < 16; ++ks){
        int kl = ks*32 + lq*8;
        int kw = kg*512 + kl;
        short8 ah = cfrag(ah_ + kl);
        short8 al = cfrag(al_ + kl);
        short8 bb = *reinterpret_cast<const short8*>(&WhhS[(lr*1024 + kw) ^ ((lr&7)<<3)]);
        acc = __builtin_amdgcn_mfma_f32_16x16x32_bf16(ah, bb, acc, 0,0,0);
        acc = __builtin_amdgcn_mfma_f32_16x16x32_bf16(al, bb, acc, 0,0,0);
      }
      if (kg == 1){
        #pragma unroll
        for (int i = 0; i < 4; ++i) partial[mwB][lane][i] = acc[i];
      }
      __syncthreads();
      if (kg == 0){
        #pragma unroll
        for (int i = 0; i < 4; ++i){
          int row = 16*mwB + lq*4 + i;
          int col = colB + lr;
          float pre = acc[i] + partial[mwB][lane][i] + xcv[i];
          float cand = tanhf(pre);
          float hnew = zv[i]*hv[i] + (1.f - zv[i])*cand;
          cstore_f32(&hfp[row*1024+col], hnew);
          unsigned short hi = f2bf(hnew);
          unsigned short lo = f2bf(hnew - bf2f(hi));
          unsigned hi2 = (unsigned)__shfl_down((int)hi, 1) & 0xffffu;
          unsigned lo2 = (unsigned)__shfl_down((int)lo, 1) & 0xffffu;
          if (!(lane & 1)){
            cstore_u32(&hhi[row*1024+col], (unsigned)hi | (hi2<<16));
            cstore_u32(&hlo[row*1024+col], (unsigned)lo | (lo2<<16));
          }
          if (h0seq)  h0seq [(size_t)t*(Bz*Hh) + row*1024 + col] = hi;
          if (outseq) outseq[(size_t)t*(Bz*Hh) + row*1024 + col] = hnew;
          if (t == Tt-1) hn[row*1024 + col] = hnew;
        }
      }
    }
    gbar(bar, &bk);
  }
}

// ---------------- host ----------------

extern "C" void kernel_launch(void* const* d_in, const int* in_sizes, int n_in,
                              void* d_out, int out_size, void* d_ws, size_t ws_size,
                              hipStream_t stream)
{
  (void)in_sizes; (void)n_in; (void)out_size; (void)ws_size;
  const float* X     = (const float*)d_in[0];
  const float* Wxrz0 = (const float*)d_in[1];
  const float* bxrz0 = (const float*)d_in[2];
  const float* Whrz0 = (const float*)d_in[3];
  const float* bhrz0 = (const float*)d_in[4];
  const float* Wxh0  = (const float*)d_in[5];
  const float* bxh0  = (const float*)d_in[6];
  const float* Whh0  = (const float*)d_in[7];
  const float* bhh0  = (const float*)d_in[8];
  const float* Wxrz1 = (const float*)d_in[9];
  const float* bxrz1 = (const float*)d_in[10];
  const float* Whrz1 = (const float*)d_in[11];
  const float* bhrz1 = (const float*)d_in[12];
  const float* Wxh1  = (const float*)d_in[13];
  const float* bxh1  = (const float*)d_in[14];
  const float* Whh1  = (const float*)d_in[15];
  const float* bhh1  = (const float*)d_in[16];

  char* p = (char*)d_ws;
  auto carve = [&](size_t bytes)->char*{
    char* r = p; p += (bytes + 255) & ~(size_t)255; return r;
  };
  unsigned short* Xbf    = (unsigned short*)carve((size_t)Mrows*512*2);
  unsigned short* W0t    = (unsigned short*)carve((size_t)3072*512*2);
  unsigned short* W1t    = (unsigned short*)carve((size_t)3072*1024*2);
  unsigned short* Whrz0t = (unsigned short*)carve((size_t)2048*1024*2);
  unsigned short* Whh0t  = (unsigned short*)carve((size_t)1024*1024*2);
  unsigned short* Whrz1t = (unsigned short*)carve((size_t)2048*1024*2);
  unsigned short* Whh1t  = (unsigned short*)carve((size_t)1024*1024*2);
  float* bias0 = (float*)carve(3072*4);
  float* bias1 = (float*)carve(3072*4);
  unsigned short* XprojRZ = (unsigned short*)carve((size_t)Mrows*2048*2);
  float*          XprojC  = (float*)carve((size_t)Mrows*1024*4);
  unsigned short* H0seq   = (unsigned short*)carve((size_t)Mrows*1024*2);
  float* hfp = (float*)carve(Bz*Hh*4);
  unsigned short* hhi  = (unsigned short*)carve(Bz*Hh*2);
  unsigned short* hlo  = (unsigned short*)carve(Bz*Hh*2);
  unsigned short* abhi = (unsigned short*)carve(Bz*Hh*2);
  unsigned short* ablo = (unsigned short*)carve(Bz*Hh*2);
  float* zbuf = (float*)carve(Bz*Hh*4);
  unsigned* bar = (unsigned*)carve(256);

  hipMemsetAsync(bar, 0, 256, stream);

  k_cvt_bf16<<<2048,256,0,stream>>>(X, Xbf, Mrows*512/4);
  k_transpose_bf16<<<dim3(8,32), 256,0,stream>>>(Wxrz0, W0t, 512, 2048);
  k_transpose_bf16<<<dim3(8,16), 256,0,stream>>>(Wxh0,  W0t + (size_t)2048*512, 512, 1024);
  k_transpose_bf16<<<dim3(16,32),256,0,stream>>>(Whrz0, Whrz0t, 1024, 2048);
  k_transpose_bf16<<<dim3(16,16),256,0,stream>>>(Whh0,  Whh0t, 1024, 1024);
  k_transpose_bf16<<<dim3(16,32),256,0,stream>>>(Wxrz1, W1t, 1024, 2048);
  k_transpose_bf16<<<dim3(16,16),256,0,stream>>>(Wxh1,  W1t + (size_t)2048*1024, 1024, 1024);
  k_transpose_bf16<<<dim3(16,32),256,0,stream>>>(Whrz1, Whrz1t, 1024, 2048);
  k_transpose_bf16<<<dim3(16,16),256,0,stream>>>(Whh1,  Whh1t, 1024, 1024);
  k_bias_fold<<<12,256,0,stream>>>(bxrz0, bhrz0, bxh0, bhh0, bias0);
  k_bias_fold<<<12,256,0,stream>>>(bxrz1, bhrz1, bxh1, bhh1, bias1);

  float* out = (float*)d_out;
  float* hn0 = out + (size_t)Mrows*Hh;
  float* hn1 = hn0 + Bz*Hh;

  // ---- layer 0 ----
  k_xproj_gemm<<<dim3(24,256),256,0,stream>>>(Xbf, W0t, bias0, XprojRZ, XprojC, 512);
  k_gru_layer<<<NBLK,512,0,stream>>>(Whrz0t, Whh0t, XprojRZ, XprojC,
                                     hfp, hhi, hlo, abhi, ablo, zbuf,
                                     H0seq, nullptr, hn0, bar);
  // ---- layer 1 ----
  k_xproj_gemm<<<dim3(24,256),256,0,stream>>>(H0seq, W1t, bias1, XprojRZ, XprojC, 1024);
  k_gru_layer<<<NBLK,512,0,stream>>>(Whrz1t, Whh1t, XprojRZ, XprojC,
                                     hfp, hhi, hlo, abhi, ablo, zbuf,
                                     nullptr, out, hn1, bar + 32);
}

// Round 4
// 29850.226 us; speedup vs baseline: 1.3098x; 1.2924x over previous
//
#include <hip/hip_runtime.h>
#include <hip/hip_bf16.h>

// GRU: T=512, B=64, Cin=512, H=1024, 2 layers.
// Round 4: persistent fence-free kernel + manually software-pipelined
// coherent loads. Round 3 was latency-bound: __hip_atomic_load in the MFMA
// loop is never pipelined by LLVM (64 serial ~600cy L3 RTTs/phase). Replace
// all hot-loop loads with inline-asm global_load (sc0 sc1 = same coherence
// as agent-scope atomics) + PF=4 register pipeline + counted vmcnt waits.

#define Hh   1024
#define Bz   64
#define Tt   512
#define Mrows (Tt*Bz)   // 32768
#define NBLK 64

typedef __attribute__((ext_vector_type(8))) short short8;
typedef __attribute__((ext_vector_type(4))) float f32x4;
typedef __attribute__((ext_vector_type(4))) unsigned int u32x4;
typedef unsigned long long u64;

__device__ __forceinline__ unsigned short f2bf(float f){
  unsigned u = __builtin_bit_cast(unsigned, f);
  u += 0x7fffu + ((u >> 16) & 1u);          // round-to-nearest-even
  return (unsigned short)(u >> 16);
}
__device__ __forceinline__ float bf2f(unsigned short s){
  unsigned u = ((unsigned)s) << 16;
  return __builtin_bit_cast(float, u);
}

// coherent stores (agent scope, relaxed): write through to the coherence point
__device__ __forceinline__ void cstore_u32(void* p, unsigned v){
  __hip_atomic_store((unsigned*)p, v, __ATOMIC_RELAXED, __HIP_MEMORY_SCOPE_AGENT);
}
__device__ __forceinline__ void cstore_f32(float* p, float v){
  __hip_atomic_store(p, v, __ATOMIC_RELAXED, __HIP_MEMORY_SCOPE_AGENT);
}

__device__ __forceinline__ void gload16(const void* g, void* l){
  __builtin_amdgcn_global_load_lds(
      (const __attribute__((address_space(1))) unsigned int*)g,
      (__attribute__((address_space(3))) unsigned int*)l, 16, 0, 0);
}

// fence-free device barrier: monotonic counter, no reset, no cache flushes.
__device__ __forceinline__ void gbar(unsigned* bar, unsigned* bk){
  __syncthreads();   // compiler drains vmcnt/lgkmcnt of every wave before s_barrier
  *bk += 1;
  if (threadIdx.x == 0){
    __hip_atomic_fetch_add(bar, 1u, __ATOMIC_RELAXED, __HIP_MEMORY_SCOPE_AGENT);
    const unsigned tgt = (*bk) * NBLK;
    while (__hip_atomic_load(bar, __ATOMIC_RELAXED, __HIP_MEMORY_SCOPE_AGENT) < tgt) {}
  }
  __syncthreads();
}

// ---- manually pipelined coherent loads ----
// 16B coherent load (bypasses stale L2; completion via counted vmcnt)
#define CLOAD16(dst, base, kk) \
  asm volatile("global_load_dwordx4 %0, %1, off offset:%c2 sc0 sc1" \
               : "=v"(dst) : "v"(base), "i"((kk)*64));
#define CLOADF(dst, addr) \
  asm volatile("global_load_dword %0, %1, off sc0 sc1" : "=v"(dst) : "v"(addr));
#define PLOADF(dst, addr) \
  asm volatile("global_load_dword %0, %1, off" : "=v"(dst) : "v"(addr));
#define PLOADU16(dst, addr) \
  asm volatile("global_load_ushort %0, %1, off" : "=v"(dst) : "v"(addr));
#define VMWAIT(n) \
  asm volatile("s_waitcnt vmcnt(%c0)" :: "i"(n) : "memory"); \
  __builtin_amdgcn_sched_barrier(0);

// ---------------- prep kernels ----------------

__global__ __launch_bounds__(256) void k_cvt_bf16(const float* __restrict__ src,
                                                  unsigned short* __restrict__ dst, int n4){
  int i = blockIdx.x*blockDim.x + threadIdx.x;
  int stride = gridDim.x*blockDim.x;
  for (; i < n4; i += stride){
    float4 v = reinterpret_cast<const float4*>(src)[i];
    ushort4 o; o.x=f2bf(v.x); o.y=f2bf(v.y); o.z=f2bf(v.z); o.w=f2bf(v.w);
    reinterpret_cast<ushort4*>(dst)[i] = o;
  }
}

// fp32 (K,N) -> bf16 (N,K), 64x64 LDS tile
__global__ __launch_bounds__(256) void k_transpose_bf16(const float* __restrict__ src,
                                                        unsigned short* __restrict__ dst,
                                                        int K, int N){
  __shared__ float tile[64][65];
  int k0 = blockIdx.x * 64, n0 = blockIdx.y * 64;
  int t = threadIdx.x;
  int r = t >> 4, c4 = (t & 15) << 2;
  #pragma unroll
  for (int j = 0; j < 4; ++j){
    const float4 v = *reinterpret_cast<const float4*>(&src[(size_t)(k0 + r + j*16) * N + n0 + c4]);
    tile[r+j*16][c4+0]=v.x; tile[r+j*16][c4+1]=v.y;
    tile[r+j*16][c4+2]=v.z; tile[r+j*16][c4+3]=v.w;
  }
  __syncthreads();
  #pragma unroll
  for (int j = 0; j < 4; ++j){
    int nn = r + j*16;
    ushort4 o;
    o.x = f2bf(tile[c4+0][nn]); o.y = f2bf(tile[c4+1][nn]);
    o.z = f2bf(tile[c4+2][nn]); o.w = f2bf(tile[c4+3][nn]);
    *reinterpret_cast<ushort4*>(&dst[(size_t)(n0+nn)*K + k0 + c4]) = o;
  }
}

__global__ void k_bias_fold(const float* __restrict__ a, const float* __restrict__ b,
                            const float* __restrict__ c, const float* __restrict__ d,
                            float* __restrict__ out){
  int i = blockIdx.x*blockDim.x + threadIdx.x;
  if (i < 2048) out[i] = a[i] + b[i];
  else if (i < 3072) out[i] = c[i-2048] + d[i-2048];
}

// ---------------- big x-projection GEMM ----------------
__global__ __launch_bounds__(256) void k_xproj_gemm(
    const unsigned short* __restrict__ A, const unsigned short* __restrict__ Bt,
    const float* __restrict__ bias, unsigned short* __restrict__ outRZ,
    float* __restrict__ outC, int K)
{
  __shared__ __align__(16) unsigned short As[128*32];
  __shared__ __align__(16) unsigned short Bs[128*32];
  const int nb = blockIdx.x, mb = blockIdx.y;
  const int m0 = mb*128, n0 = nb*128;
  const int t = threadIdx.x, lane = t & 63, w = t >> 6;
  const int wr = w >> 1, wc = w & 1;
  const int lr = lane & 15, lq = lane >> 4;
  const int sr = t >> 2, scg = t & 3;
  f32x4 acc[4][4];
  const f32x4 zero4 = {0.f,0.f,0.f,0.f};
  #pragma unroll
  for (int mt=0;mt<4;++mt)
    #pragma unroll
    for (int nt=0;nt<4;++nt) acc[mt][nt] = zero4;

  const unsigned short* ga0 = &A [(size_t)(m0 + sr     )*K + scg*8];
  const unsigned short* ga1 = &A [(size_t)(m0 + sr + 64)*K + scg*8];
  const unsigned short* gb0 = &Bt[(size_t)(n0 + sr     )*K + scg*8];
  const unsigned short* gb1 = &Bt[(size_t)(n0 + sr + 64)*K + scg*8];
  char* lA = (char*)As + w*1024;
  char* lB = (char*)Bs + w*1024;
  const int kiters = K >> 5;
  for (int kt = 0; kt < kiters; ++kt){
    __syncthreads();
    gload16(ga0 + kt*32, lA);
    gload16(ga1 + kt*32, lA + 4096);
    gload16(gb0 + kt*32, lB);
    gload16(gb1 + kt*32, lB + 4096);
    asm volatile("s_waitcnt vmcnt(0)" ::: "memory");
    __syncthreads();
    short8 af[4], bfr[4];
    #pragma unroll
    for (int mt=0; mt<4; ++mt)
      af[mt] = *reinterpret_cast<const short8*>(&As[(wr*64 + mt*16 + lr)*32 + lq*8]);
    #pragma unroll
    for (int nt=0; nt<4; ++nt)
      bfr[nt] = *reinterpret_cast<const short8*>(&Bs[(wc*64 + nt*16 + lr)*32 + lq*8]);
    #pragma unroll
    for (int mt=0; mt<4; ++mt)
      #pragma unroll
      for (int nt=0; nt<4; ++nt)
        acc[mt][nt] = __builtin_amdgcn_mfma_f32_16x16x32_bf16(af[mt], bfr[nt], acc[mt][nt], 0,0,0);
  }
  const bool isRZ = (n0 < 2048);
  #pragma unroll
  for (int mt=0;mt<4;++mt){
    #pragma unroll
    for (int nt=0;nt<4;++nt){
      int gn = n0 + wc*64 + nt*16 + lr;
      float bv = bias[gn];
      #pragma unroll
      for (int i=0;i<4;++i){
        int gm = m0 + wr*64 + mt*16 + lq*4 + i;
        float v = acc[mt][nt][i] + bv;
        if (isRZ) outRZ[(size_t)gm*2048 + gn] = f2bf(v);
        else      outC [(size_t)gm*1024 + (gn - 2048)] = v;
      }
    }
  }
}

// ---------------- persistent per-layer recurrent kernel ----------------
// 64 blocks x 512 threads (1 block/CU). Block b:
//   phase A: rz cols [32b,32b+32): 8 waves = (m-tile 0-3) x (n-half 0-1)
//   phase B: cand cols [16b,16b+16): 8 waves = (m-tile 0-3) x (k-half 0-1)
__global__ __launch_bounds__(512) void k_gru_layer(
    const unsigned short* __restrict__ Wrzg,   // (2048,1024) bf16
    const unsigned short* __restrict__ Whhg,   // (1024,1024) bf16
    const unsigned short* __restrict__ XprojRZ,// (T,64,2048) bf16, biases folded
    const float* __restrict__ XprojC,          // (T,64,1024) fp32, biases folded
    float* hfp, unsigned short* hhi, unsigned short* hlo,
    unsigned short* abhi, unsigned short* ablo,
    float* zbuf,
    unsigned short* __restrict__ h0seq,        // L0: bf16 sequence out (else null)
    float* __restrict__ outseq,                // L1: fp32 sequence out (else null)
    float* __restrict__ hn,                    // final h slot
    unsigned* bar)
{
  __shared__ __align__(16) unsigned short WrzS[32*1024];  // 64KB, XOR-swizzled
  __shared__ __align__(16) unsigned short WhhS[16*1024];  // 32KB
  __shared__ float partial[4][64][5];                     // stride-5: conflict-free

  const int b   = blockIdx.x;
  const int tid = threadIdx.x;
  const int lane = tid & 63, w = tid >> 6;
  const int lr = lane & 15, lq = lane >> 4;
  unsigned bk = 0;

  // ---- stage weights into LDS (once) ----
  #pragma unroll
  for (int j = 0; j < 8; ++j){
    int lin = (tid + j*512) * 8;
    int n = lin >> 10, k = lin & 1023;
    short8 v = *reinterpret_cast<const short8*>(&Wrzg[(size_t)(32*b + n)*1024 + k]);
    *reinterpret_cast<short8*>(&WrzS[(n*1024 + k) ^ ((n&7)<<3)]) = v;
  }
  #pragma unroll
  for (int j = 0; j < 4; ++j){
    int lin = (tid + j*512) * 8;
    int n = lin >> 10, k = lin & 1023;
    short8 v = *reinterpret_cast<const short8*>(&Whhg[(size_t)(16*b + n)*1024 + k]);
    *reinterpret_cast<short8*>(&WhhS[(n*1024 + k) ^ ((n&7)<<3)]) = v;
  }
  // ---- zero my h slice cols [16b,16b+16) with coherent stores (ws poisoned) ----
  {
    int r = tid >> 3, cp = (tid & 7) * 2;
    cstore_u32(&hhi[r*1024 + 16*b + cp], 0u);
    cstore_u32(&hlo[r*1024 + 16*b + cp], 0u);
    int r2 = tid >> 4, c2 = 16*b + (tid & 15);
    cstore_f32(&hfp[r2*1024 + c2], 0.f);
    cstore_f32(&hfp[(r2+32)*1024 + c2], 0.f);
  }
  gbar(bar, &bk);

  const bool isR = (b < 32);
  // phase A wave mapping
  const int mwA = w >> 1, nhA = w & 1;
  const int rowA = 16*mwA;
  const int colA = 32*b + 16*nhA;
  const int nloc = 16*nhA + lr;
  // phase B wave mapping
  const int mwB = w & 3, kg = w >> 2;
  const int colB = 16*b;

  for (int t = 0; t < Tt; ++t){
    // ================= phase A: rz preact + gates =================
    {
      const unsigned short* xp = XprojRZ + (size_t)t*Bz*2048;
      // hoisted epilogue loads (issued first; in-order vmcnt covers them
      // by the time the first pipelined iteration waits)
      unsigned xvu[4]; float hv[4];
      #pragma unroll
      for (int i = 0; i < 4; ++i){
        const unsigned short* a = &xp[(rowA + lq*4 + i)*2048 + colA + lr];
        PLOADU16(xvu[i], a);
      }
      if (isR){
        #pragma unroll
        for (int i = 0; i < 4; ++i){
          const float* a = &hfp[(rowA + lq*4 + i)*1024 + colA + lr];
          CLOADF(hv[i], a);
        }
      }
      const unsigned short* hhp = hhi + (rowA + lr)*1024 + lq*8;
      const unsigned short* hlp = hlo + (rowA + lr)*1024 + lq*8;
      u32x4 ahv[4], alv[4];
      CLOAD16(ahv[0], hhp, 0) CLOAD16(alv[0], hlp, 0)
      CLOAD16(ahv[1], hhp, 1) CLOAD16(alv[1], hlp, 1)
      CLOAD16(ahv[2], hhp, 2) CLOAD16(alv[2], hlp, 2)
      CLOAD16(ahv[3], hhp, 3) CLOAD16(alv[3], hlp, 3)
      f32x4 acc0 = {0.f,0.f,0.f,0.f}, acc1 = {0.f,0.f,0.f,0.f};
      #pragma unroll
      for (int k = 0; k < 32; ++k){
        const int slot = k & 3;
        VMWAIT(k < 28 ? 6 : 62 - 2*k)
        short8 ah = __builtin_bit_cast(short8, ahv[slot]);
        short8 al = __builtin_bit_cast(short8, alv[slot]);
        short8 bb = *reinterpret_cast<const short8*>(
            &WrzS[(nloc*1024 + k*32 + lq*8) ^ ((nloc&7)<<3)]);
        acc0 = __builtin_amdgcn_mfma_f32_16x16x32_bf16(ah, bb, acc0, 0,0,0);
        acc1 = __builtin_amdgcn_mfma_f32_16x16x32_bf16(al, bb, acc1, 0,0,0);
        if (k < 28){ CLOAD16(ahv[slot], hhp, k+4) CLOAD16(alv[slot], hlp, k+4) }
      }
      #pragma unroll
      for (int i = 0; i < 4; ++i){
        int row = rowA + lq*4 + i;
        int col = colA + lr;
        float pre = acc0[i] + acc1[i] + bf2f((unsigned short)xvu[i]);
        float s = 1.f / (1.f + __expf(-pre));
        if (isR){
          float av = hv[i] * s;
          unsigned short hi = f2bf(av);
          unsigned short lo = f2bf(av - bf2f(hi));
          unsigned hi2 = (unsigned)__shfl_down((int)hi, 1) & 0xffffu;
          unsigned lo2 = (unsigned)__shfl_down((int)lo, 1) & 0xffffu;
          if (!(lane & 1)){
            cstore_u32(&abhi[row*1024+col], (unsigned)hi | (hi2<<16));
            cstore_u32(&ablo[row*1024+col], (unsigned)lo | (lo2<<16));
          }
        } else {
          cstore_f32(&zbuf[row*1024 + col - 1024], s);
        }
      }
    }
    gbar(bar, &bk);
    // ================= phase B: cand + state update =================
    {
      const float* xc_t = XprojC + (size_t)t*Bz*1024;
      float xcv[4], zv[4], hv[4];
      if (kg == 0){
        #pragma unroll
        for (int i = 0; i < 4; ++i){
          int row = 16*mwB + lq*4 + i, col = colB + lr;
          PLOADF(xcv[i], &xc_t[row*1024 + col]);
          CLOADF(zv[i],  &zbuf[row*1024 + col]);
          CLOADF(hv[i],  &hfp [row*1024 + col]);
        }
      }
      const unsigned short* ahp = abhi + (16*mwB + lr)*1024 + kg*512 + lq*8;
      const unsigned short* alp = ablo + (16*mwB + lr)*1024 + kg*512 + lq*8;
      u32x4 ahv[4], alv[4];
      CLOAD16(ahv[0], ahp, 0) CLOAD16(alv[0], alp, 0)
      CLOAD16(ahv[1], ahp, 1) CLOAD16(alv[1], alp, 1)
      CLOAD16(ahv[2], ahp, 2) CLOAD16(alv[2], alp, 2)
      CLOAD16(ahv[3], ahp, 3) CLOAD16(alv[3], alp, 3)
      f32x4 acc0 = {0.f,0.f,0.f,0.f}, acc1 = {0.f,0.f,0.f,0.f};
      #pragma unroll
      for (int k = 0; k < 16; ++k){
        const int slot = k & 3;
        VMWAIT(k < 12 ? 6 : 30 - 2*k)
        short8 ah = __builtin_bit_cast(short8, ahv[slot]);
        short8 al = __builtin_bit_cast(short8, alv[slot]);
        short8 bb = *reinterpret_cast<const short8*>(
            &WhhS[(lr*1024 + kg*512 + k*32 + lq*8) ^ ((lr&7)<<3)]);
        acc0 = __builtin_amdgcn_mfma_f32_16x16x32_bf16(ah, bb, acc0, 0,0,0);
        acc1 = __builtin_amdgcn_mfma_f32_16x16x32_bf16(al, bb, acc1, 0,0,0);
        if (k < 12){ CLOAD16(ahv[slot], ahp, k+4) CLOAD16(alv[slot], alp, k+4) }
      }
      if (kg == 1){
        #pragma unroll
        for (int i = 0; i < 4; ++i) partial[mwB][lane][i] = acc0[i] + acc1[i];
      }
      __syncthreads();
      if (kg == 0){
        #pragma unroll
        for (int i = 0; i < 4; ++i){
          int row = 16*mwB + lq*4 + i;
          int col = colB + lr;
          float pre = acc0[i] + acc1[i] + partial[mwB][lane][i] + xcv[i];
          float cand = tanhf(pre);
          float hnew = zv[i]*hv[i] + (1.f - zv[i])*cand;
          cstore_f32(&hfp[row*1024+col], hnew);
          unsigned short hi = f2bf(hnew);
          unsigned short lo = f2bf(hnew - bf2f(hi));
          unsigned hi2 = (unsigned)__shfl_down((int)hi, 1) & 0xffffu;
          unsigned lo2 = (unsigned)__shfl_down((int)lo, 1) & 0xffffu;
          if (!(lane & 1)){
            cstore_u32(&hhi[row*1024+col], (unsigned)hi | (hi2<<16));
            cstore_u32(&hlo[row*1024+col], (unsigned)lo | (lo2<<16));
          }
          if (h0seq)  h0seq [(size_t)t*(Bz*Hh) + row*1024 + col] = hi;
          if (outseq) outseq[(size_t)t*(Bz*Hh) + row*1024 + col] = hnew;
          if (t == Tt-1) hn[row*1024 + col] = hnew;
        }
      }
    }
    gbar(bar, &bk);
  }
}

// ---------------- host ----------------

extern "C" void kernel_launch(void* const* d_in, const int* in_sizes, int n_in,
                              void* d_out, int out_size, void* d_ws, size_t ws_size,
                              hipStream_t stream)
{
  (void)in_sizes; (void)n_in; (void)out_size; (void)ws_size;
  const float* X     = (const float*)d_in[0];
  const float* Wxrz0 = (const float*)d_in[1];
  const float* bxrz0 = (const float*)d_in[2];
  const float* Whrz0 = (const float*)d_in[3];
  const float* bhrz0 = (const float*)d_in[4];
  const float* Wxh0  = (const float*)d_in[5];
  const float* bxh0  = (const float*)d_in[6];
  const float* Whh0  = (const float*)d_in[7];
  const float* bhh0  = (const float*)d_in[8];
  const float* Wxrz1 = (const float*)d_in[9];
  const float* bxrz1 = (const float*)d_in[10];
  const float* Whrz1 = (const float*)d_in[11];
  const float* bhrz1 = (const float*)d_in[12];
  const float* Wxh1  = (const float*)d_in[13];
  const float* bxh1  = (const float*)d_in[14];
  const float* Whh1  = (const float*)d_in[15];
  const float* bhh1  = (const float*)d_in[16];

  char* p = (char*)d_ws;
  auto carve = [&](size_t bytes)->char*{
    char* r = p; p += (bytes + 255) & ~(size_t)255; return r;
  };
  unsigned short* Xbf    = (unsigned short*)carve((size_t)Mrows*512*2);
  unsigned short* W0t    = (unsigned short*)carve((size_t)3072*512*2);
  unsigned short* W1t    = (unsigned short*)carve((size_t)3072*1024*2);
  unsigned short* Whrz0t = (unsigned short*)carve((size_t)2048*1024*2);
  unsigned short* Whh0t  = (unsigned short*)carve((size_t)1024*1024*2);
  unsigned short* Whrz1t = (unsigned short*)carve((size_t)2048*1024*2);
  unsigned short* Whh1t  = (unsigned short*)carve((size_t)1024*1024*2);
  float* bias0 = (float*)carve(3072*4);
  float* bias1 = (float*)carve(3072*4);
  unsigned short* XprojRZ = (unsigned short*)carve((size_t)Mrows*2048*2);
  float*          XprojC  = (float*)carve((size_t)Mrows*1024*4);
  unsigned short* H0seq   = (unsigned short*)carve((size_t)Mrows*1024*2);
  float* hfp = (float*)carve(Bz*Hh*4);
  unsigned short* hhi  = (unsigned short*)carve(Bz*Hh*2);
  unsigned short* hlo  = (unsigned short*)carve(Bz*Hh*2);
  unsigned short* abhi = (unsigned short*)carve(Bz*Hh*2);
  unsigned short* ablo = (unsigned short*)carve(Bz*Hh*2);
  float* zbuf = (float*)carve(Bz*Hh*4);
  unsigned* bar = (unsigned*)carve(256);

  hipMemsetAsync(bar, 0, 256, stream);

  k_cvt_bf16<<<2048,256,0,stream>>>(X, Xbf, Mrows*512/4);
  k_transpose_bf16<<<dim3(8,32), 256,0,stream>>>(Wxrz0, W0t, 512, 2048);
  k_transpose_bf16<<<dim3(8,16), 256,0,stream>>>(Wxh0,  W0t + (size_t)2048*512, 512, 1024);
  k_transpose_bf16<<<dim3(16,32),256,0,stream>>>(Whrz0, Whrz0t, 1024, 2048);
  k_transpose_bf16<<<dim3(16,16),256,0,stream>>>(Whh0,  Whh0t, 1024, 1024);
  k_transpose_bf16<<<dim3(16,32),256,0,stream>>>(Wxrz1, W1t, 1024, 2048);
  k_transpose_bf16<<<dim3(16,16),256,0,stream>>>(Wxh1,  W1t + (size_t)2048*1024, 1024, 1024);
  k_transpose_bf16<<<dim3(16,32),256,0,stream>>>(Whrz1, Whrz1t, 1024, 2048);
  k_transpose_bf16<<<dim3(16,16),256,0,stream>>>(Whh1,  Whh1t, 1024, 1024);
  k_bias_fold<<<12,256,0,stream>>>(bxrz0, bhrz0, bxh0, bhh0, bias0);
  k_bias_fold<<<12,256,0,stream>>>(bxrz1, bhrz1, bxh1, bhh1, bias1);

  float* out = (float*)d_out;
  float* hn0 = out + (size_t)Mrows*Hh;
  float* hn1 = hn0 + Bz*Hh;

  // ---- layer 0 ----
  k_xproj_gemm<<<dim3(24,256),256,0,stream>>>(Xbf, W0t, bias0, XprojRZ, XprojC, 512);
  k_gru_layer<<<NBLK,512,0,stream>>>(Whrz0t, Whh0t, XprojRZ, XprojC,
                                     hfp, hhi, hlo, abhi, ablo, zbuf,
                                     H0seq, nullptr, hn0, bar);
  // ---- layer 1 ----
  k_xproj_gemm<<<dim3(24,256),256,0,stream>>>(H0seq, W1t, bias1, XprojRZ, XprojC, 1024);
  k_gru_layer<<<NBLK,512,0,stream>>>(Whrz1t, Whh1t, XprojRZ, XprojC,
                                     hfp, hhi, hlo, abhi, ablo, zbuf,
                                     nullptr, out, hn1, bar + 32);
}

// Round 5
// 20817.084 us; speedup vs baseline: 1.8782x; 1.4339x over previous
//
#include <hip/hip_runtime.h>
#include <hip/hip_bf16.h>

// GRU: T=512, B=64, Cin=512, H=1024, 2 layers.
// Round 5: minimize device-coherent traffic. Block b owns columns
// [16b,16b+16) of r, z, cand, and h. z + fp32 h are BLOCK-LOCAL (LDS).
// Phase A is K-split (like phase B) so each block reads the h broadcast
// exactly once per step. Only cross-block state: a(hi/lo), h(hi/lo).

#define Hh   1024
#define Bz   64
#define Tt   512
#define Mrows (Tt*Bz)   // 32768
#define NBLK 64

typedef __attribute__((ext_vector_type(8))) short short8;
typedef __attribute__((ext_vector_type(4))) float f32x4;
typedef __attribute__((ext_vector_type(4))) unsigned int u32x4;

__device__ __forceinline__ unsigned short f2bf(float f){
  unsigned u = __builtin_bit_cast(unsigned, f);
  u += 0x7fffu + ((u >> 16) & 1u);          // round-to-nearest-even
  return (unsigned short)(u >> 16);
}
__device__ __forceinline__ float bf2f(unsigned short s){
  unsigned u = ((unsigned)s) << 16;
  return __builtin_bit_cast(float, u);
}

// coherent stores (agent scope, relaxed)
__device__ __forceinline__ void cstore_u32(void* p, unsigned v){
  __hip_atomic_store((unsigned*)p, v, __ATOMIC_RELAXED, __HIP_MEMORY_SCOPE_AGENT);
}

__device__ __forceinline__ void gload16(const void* g, void* l){
  __builtin_amdgcn_global_load_lds(
      (const __attribute__((address_space(1))) unsigned int*)g,
      (__attribute__((address_space(3))) unsigned int*)l, 16, 0, 0);
}

// fence-free device barrier: monotonic counter, no reset, no cache flushes.
__device__ __forceinline__ void gbar(unsigned* bar, unsigned* bk){
  __syncthreads();
  *bk += 1;
  if (threadIdx.x == 0){
    __hip_atomic_fetch_add(bar, 1u, __ATOMIC_RELAXED, __HIP_MEMORY_SCOPE_AGENT);
    const unsigned tgt = (*bk) * NBLK;
    while (__hip_atomic_load(bar, __ATOMIC_RELAXED, __HIP_MEMORY_SCOPE_AGENT) < tgt)
      __builtin_amdgcn_s_sleep(1);
  }
  __syncthreads();
}

// ---- manually pipelined coherent loads ----
#define CLOAD16(dst, base, kk) \
  asm volatile("global_load_dwordx4 %0, %1, off offset:%c2 sc0 sc1" \
               : "=v"(dst) : "v"(base), "i"((kk)*64));
#define PLOADF(dst, addr) \
  asm volatile("global_load_dword %0, %1, off" : "=v"(dst) : "v"(addr));
#define PLOADU16(dst, addr) \
  asm volatile("global_load_ushort %0, %1, off" : "=v"(dst) : "v"(addr));
#define VMWAIT(n) \
  asm volatile("s_waitcnt vmcnt(%c0)" :: "i"(n) : "memory"); \
  __builtin_amdgcn_sched_barrier(0);

// ---------------- prep kernels ----------------

__global__ __launch_bounds__(256) void k_cvt_bf16(const float* __restrict__ src,
                                                  unsigned short* __restrict__ dst, int n4){
  int i = blockIdx.x*blockDim.x + threadIdx.x;
  int stride = gridDim.x*blockDim.x;
  for (; i < n4; i += stride){
    float4 v = reinterpret_cast<const float4*>(src)[i];
    ushort4 o; o.x=f2bf(v.x); o.y=f2bf(v.y); o.z=f2bf(v.z); o.w=f2bf(v.w);
    reinterpret_cast<ushort4*>(dst)[i] = o;
  }
}

// fp32 (K,N) -> bf16 (N,K), 64x64 LDS tile
__global__ __launch_bounds__(256) void k_transpose_bf16(const float* __restrict__ src,
                                                        unsigned short* __restrict__ dst,
                                                        int K, int N){
  __shared__ float tile[64][65];
  int k0 = blockIdx.x * 64, n0 = blockIdx.y * 64;
  int t = threadIdx.x;
  int r = t >> 4, c4 = (t & 15) << 2;
  #pragma unroll
  for (int j = 0; j < 4; ++j){
    const float4 v = *reinterpret_cast<const float4*>(&src[(size_t)(k0 + r + j*16) * N + n0 + c4]);
    tile[r+j*16][c4+0]=v.x; tile[r+j*16][c4+1]=v.y;
    tile[r+j*16][c4+2]=v.z; tile[r+j*16][c4+3]=v.w;
  }
  __syncthreads();
  #pragma unroll
  for (int j = 0; j < 4; ++j){
    int nn = r + j*16;
    ushort4 o;
    o.x = f2bf(tile[c4+0][nn]); o.y = f2bf(tile[c4+1][nn]);
    o.z = f2bf(tile[c4+2][nn]); o.w = f2bf(tile[c4+3][nn]);
    *reinterpret_cast<ushort4*>(&dst[(size_t)(n0+nn)*K + k0 + c4]) = o;
  }
}

__global__ void k_bias_fold(const float* __restrict__ a, const float* __restrict__ b,
                            const float* __restrict__ c, const float* __restrict__ d,
                            float* __restrict__ out){
  int i = blockIdx.x*blockDim.x + threadIdx.x;
  if (i < 2048) out[i] = a[i] + b[i];
  else if (i < 3072) out[i] = c[i-2048] + d[i-2048];
}

// ---------------- big x-projection GEMM ----------------
__global__ __launch_bounds__(256) void k_xproj_gemm(
    const unsigned short* __restrict__ A, const unsigned short* __restrict__ Bt,
    const float* __restrict__ bias, unsigned short* __restrict__ outRZ,
    float* __restrict__ outC, int K)
{
  __shared__ __align__(16) unsigned short As[128*32];
  __shared__ __align__(16) unsigned short Bs[128*32];
  const int nb = blockIdx.x, mb = blockIdx.y;
  const int m0 = mb*128, n0 = nb*128;
  const int t = threadIdx.x, lane = t & 63, w = t >> 6;
  const int wr = w >> 1, wc = w & 1;
  const int lr = lane & 15, lq = lane >> 4;
  const int sr = t >> 2, scg = t & 3;
  f32x4 acc[4][4];
  const f32x4 zero4 = {0.f,0.f,0.f,0.f};
  #pragma unroll
  for (int mt=0;mt<4;++mt)
    #pragma unroll
    for (int nt=0;nt<4;++nt) acc[mt][nt] = zero4;

  const unsigned short* ga0 = &A [(size_t)(m0 + sr     )*K + scg*8];
  const unsigned short* ga1 = &A [(size_t)(m0 + sr + 64)*K + scg*8];
  const unsigned short* gb0 = &Bt[(size_t)(n0 + sr     )*K + scg*8];
  const unsigned short* gb1 = &Bt[(size_t)(n0 + sr + 64)*K + scg*8];
  char* lA = (char*)As + w*1024;
  char* lB = (char*)Bs + w*1024;
  const int kiters = K >> 5;
  for (int kt = 0; kt < kiters; ++kt){
    __syncthreads();
    gload16(ga0 + kt*32, lA);
    gload16(ga1 + kt*32, lA + 4096);
    gload16(gb0 + kt*32, lB);
    gload16(gb1 + kt*32, lB + 4096);
    asm volatile("s_waitcnt vmcnt(0)" ::: "memory");
    __syncthreads();
    short8 af[4], bfr[4];
    #pragma unroll
    for (int mt=0; mt<4; ++mt)
      af[mt] = *reinterpret_cast<const short8*>(&As[(wr*64 + mt*16 + lr)*32 + lq*8]);
    #pragma unroll
    for (int nt=0; nt<4; ++nt)
      bfr[nt] = *reinterpret_cast<const short8*>(&Bs[(wc*64 + nt*16 + lr)*32 + lq*8]);
    #pragma unroll
    for (int mt=0; mt<4; ++mt)
      #pragma unroll
      for (int nt=0; nt<4; ++nt)
        acc[mt][nt] = __builtin_amdgcn_mfma_f32_16x16x32_bf16(af[mt], bfr[nt], acc[mt][nt], 0,0,0);
  }
  const bool isRZ = (n0 < 2048);
  #pragma unroll
  for (int mt=0;mt<4;++mt){
    #pragma unroll
    for (int nt=0;nt<4;++nt){
      int gn = n0 + wc*64 + nt*16 + lr;
      float bv = bias[gn];
      #pragma unroll
      for (int i=0;i<4;++i){
        int gm = m0 + wr*64 + mt*16 + lq*4 + i;
        float v = acc[mt][nt][i] + bv;
        if (isRZ) outRZ[(size_t)gm*2048 + gn] = f2bf(v);
        else      outC [(size_t)gm*1024 + (gn - 2048)] = v;
      }
    }
  }
}

// ---------------- persistent per-layer recurrent kernel ----------------
// 64 blocks x 512 threads (1 block/CU). Block b owns cols [16b,16b+16) of
// r, z, cand, h. Both phases: waves = (m-tile 0-3) x (K-half 0-1), LDS
// partial combine. Cross-block state: only a(hi/lo) and h(hi/lo), bf16.
__global__ __launch_bounds__(512) void k_gru_layer(
    const unsigned short* __restrict__ Wrzg,   // (2048,1024) bf16
    const unsigned short* __restrict__ Whhg,   // (1024,1024) bf16
    const unsigned short* __restrict__ XprojRZ,// (T,64,2048) bf16, biases folded
    const float* __restrict__ XprojC,          // (T,64,1024) fp32, biases folded
    unsigned short* hhi, unsigned short* hlo,
    unsigned short* abhi, unsigned short* ablo,
    unsigned short* __restrict__ h0seq,        // L0: bf16 sequence out (else null)
    float* __restrict__ outseq,                // L1: fp32 sequence out (else null)
    float* __restrict__ hn,                    // final h slot
    unsigned* bar)
{
  __shared__ __align__(16) unsigned short WrzS[32*1024]; // 64KB rows0-15=r,16-31=z
  __shared__ __align__(16) unsigned short WhhS[16*1024]; // 32KB
  __shared__ float hloc[64][17];                         // block's fp32 h slice
  __shared__ float zloc[64][17];                         // block's z slice
  __shared__ float partial[4][64][9];                    // K-split combine

  const int b   = blockIdx.x;
  const int tid = threadIdx.x;
  const int lane = tid & 63, w = tid >> 6;
  const int lr = lane & 15, lq = lane >> 4;
  unsigned bk = 0;

  // ---- stage weights into LDS (once), XOR-swizzled ----
  #pragma unroll
  for (int j = 0; j < 8; ++j){
    int lin = (tid + j*512) * 8;
    int n = lin >> 10, k = lin & 1023;
    int gr = (n < 16) ? (16*b + n) : (1024 + 16*b + (n - 16));
    short8 v = *reinterpret_cast<const short8*>(&Wrzg[(size_t)gr*1024 + k]);
    *reinterpret_cast<short8*>(&WrzS[(n*1024 + k) ^ ((n&7)<<3)]) = v;
  }
  #pragma unroll
  for (int j = 0; j < 4; ++j){
    int lin = (tid + j*512) * 8;
    int n = lin >> 10, k = lin & 1023;
    short8 v = *reinterpret_cast<const short8*>(&Whhg[(size_t)(16*b + n)*1024 + k]);
    *reinterpret_cast<short8*>(&WhhS[(n*1024 + k) ^ ((n&7)<<3)]) = v;
  }
  // ---- zero local h and the global h broadcast slice (ws is poisoned) ----
  for (int idx = tid; idx < 64*17; idx += 512) ((float*)hloc)[idx] = 0.f;
  {
    int r = tid >> 3, cp = (tid & 7) * 2;
    cstore_u32(&hhi[r*1024 + 16*b + cp], 0u);
    cstore_u32(&hlo[r*1024 + 16*b + cp], 0u);
  }
  gbar(bar, &bk);

  const int mt = w & 3, kh = w >> 2;   // wave = (m-tile, K-half) in both phases
  const int rA = 16*mt;                // batch-row tile base
  const int kb = kh*512;               // K-half base

  for (int t = 0; t < Tt; ++t){
    // ================= phase A: rz preact + gates =================
    {
      const unsigned short* xp = XprojRZ + (size_t)t*Bz*2048;
      // hoisted epilogue loads (uniform addresses across kh for vmcnt parity)
      unsigned xr[4], xz[4];
      #pragma unroll
      for (int i = 0; i < 4; ++i){
        PLOADU16(xr[i], &xp[(rA + lq*4 + i)*2048 + 16*b + lr]);
        PLOADU16(xz[i], &xp[(rA + lq*4 + i)*2048 + 1024 + 16*b + lr]);
      }
      const unsigned short* hhp = hhi + (rA + lr)*1024 + kb + lq*8;
      const unsigned short* hlp = hlo + (rA + lr)*1024 + kb + lq*8;
      u32x4 ahv[4], alv[4];
      CLOAD16(ahv[0], hhp, 0) CLOAD16(alv[0], hlp, 0)
      CLOAD16(ahv[1], hhp, 1) CLOAD16(alv[1], hlp, 1)
      CLOAD16(ahv[2], hhp, 2) CLOAD16(alv[2], hlp, 2)
      CLOAD16(ahv[3], hhp, 3) CLOAD16(alv[3], hlp, 3)
      f32x4 accr0={0,0,0,0}, accr1={0,0,0,0}, accz0={0,0,0,0}, accz1={0,0,0,0};
      #pragma unroll
      for (int k = 0; k < 16; ++k){
        const int slot = k & 3;
        VMWAIT(k < 12 ? 6 : 30 - 2*k)
        short8 ah = __builtin_bit_cast(short8, ahv[slot]);
        short8 al = __builtin_bit_cast(short8, alv[slot]);
        short8 br = *reinterpret_cast<const short8*>(
            &WrzS[(lr*1024 + kb + k*32 + lq*8) ^ ((lr&7)<<3)]);
        short8 bz = *reinterpret_cast<const short8*>(
            &WrzS[((16+lr)*1024 + kb + k*32 + lq*8) ^ ((lr&7)<<3)]);
        accr0 = __builtin_amdgcn_mfma_f32_16x16x32_bf16(ah, br, accr0, 0,0,0);
        accr1 = __builtin_amdgcn_mfma_f32_16x16x32_bf16(al, br, accr1, 0,0,0);
        accz0 = __builtin_amdgcn_mfma_f32_16x16x32_bf16(ah, bz, accz0, 0,0,0);
        accz1 = __builtin_amdgcn_mfma_f32_16x16x32_bf16(al, bz, accz1, 0,0,0);
        if (k < 12){ CLOAD16(ahv[slot], hhp, k+4) CLOAD16(alv[slot], hlp, k+4) }
      }
      f32x4 accr = accr0 + accr1, accz = accz0 + accz1;
      if (kh == 1){
        #pragma unroll
        for (int i = 0; i < 4; ++i){
          partial[mt][lane][i]   = accr[i];
          partial[mt][lane][4+i] = accz[i];
        }
      }
      __syncthreads();
      if (kh == 0){
        #pragma unroll
        for (int i = 0; i < 4; ++i){
          int row = rA + lq*4 + i;
          float pr = accr[i] + partial[mt][lane][i]   + bf2f((unsigned short)xr[i]);
          float pz = accz[i] + partial[mt][lane][4+i] + bf2f((unsigned short)xz[i]);
          float rg = 1.f / (1.f + __expf(-pr));
          float zg = 1.f / (1.f + __expf(-pz));
          zloc[row][lr] = zg;
          float av = hloc[row][lr] * rg;
          unsigned short hi = f2bf(av);
          unsigned short lo = f2bf(av - bf2f(hi));
          unsigned hi2 = (unsigned)__shfl_down((int)hi, 1) & 0xffffu;
          unsigned lo2 = (unsigned)__shfl_down((int)lo, 1) & 0xffffu;
          if (!(lane & 1)){
            cstore_u32(&abhi[row*1024 + 16*b + lr], (unsigned)hi | (hi2<<16));
            cstore_u32(&ablo[row*1024 + 16*b + lr], (unsigned)lo | (lo2<<16));
          }
        }
      }
    }
    gbar(bar, &bk);
    // ================= phase B: cand + state update =================
    {
      const float* xc_t = XprojC + (size_t)t*Bz*1024;
      float xcv[4];
      #pragma unroll
      for (int i = 0; i < 4; ++i)
        PLOADF(xcv[i], &xc_t[(rA + lq*4 + i)*1024 + 16*b + lr]);
      const unsigned short* ahp = abhi + (rA + lr)*1024 + kb + lq*8;
      const unsigned short* alp = ablo + (rA + lr)*1024 + kb + lq*8;
      u32x4 ahv[4], alv[4];
      CLOAD16(ahv[0], ahp, 0) CLOAD16(alv[0], alp, 0)
      CLOAD16(ahv[1], ahp, 1) CLOAD16(alv[1], alp, 1)
      CLOAD16(ahv[2], ahp, 2) CLOAD16(alv[2], alp, 2)
      CLOAD16(ahv[3], ahp, 3) CLOAD16(alv[3], alp, 3)
      f32x4 acc0={0,0,0,0}, acc1={0,0,0,0};
      #pragma unroll
      for (int k = 0; k < 16; ++k){
        const int slot = k & 3;
        VMWAIT(k < 12 ? 6 : 30 - 2*k)
        short8 ah = __builtin_bit_cast(short8, ahv[slot]);
        short8 al = __builtin_bit_cast(short8, alv[slot]);
        short8 bb = *reinterpret_cast<const short8*>(
            &WhhS[(lr*1024 + kb + k*32 + lq*8) ^ ((lr&7)<<3)]);
        acc0 = __builtin_amdgcn_mfma_f32_16x16x32_bf16(ah, bb, acc0, 0,0,0);
        acc1 = __builtin_amdgcn_mfma_f32_16x16x32_bf16(al, bb, acc1, 0,0,0);
        if (k < 12){ CLOAD16(ahv[slot], ahp, k+4) CLOAD16(alv[slot], alp, k+4) }
      }
      f32x4 acc = acc0 + acc1;
      if (kh == 1){
        #pragma unroll
        for (int i = 0; i < 4; ++i) partial[mt][lane][i] = acc[i];
      }
      __syncthreads();
      if (kh == 0){
        #pragma unroll
        for (int i = 0; i < 4; ++i){
          int row = rA + lq*4 + i;
          int col = 16*b + lr;
          float pre = acc[i] + partial[mt][lane][i] + xcv[i];
          float cand = tanhf(pre);
          float zg = zloc[row][lr];
          float h  = hloc[row][lr];
          float hnew = zg*h + (1.f - zg)*cand;
          hloc[row][lr] = hnew;
          unsigned short hi = f2bf(hnew);
          unsigned short lo = f2bf(hnew - bf2f(hi));
          unsigned hi2 = (unsigned)__shfl_down((int)hi, 1) & 0xffffu;
          unsigned lo2 = (unsigned)__shfl_down((int)lo, 1) & 0xffffu;
          if (!(lane & 1)){
            cstore_u32(&hhi[row*1024 + col], (unsigned)hi | (hi2<<16));
            cstore_u32(&hlo[row*1024 + col], (unsigned)lo | (lo2<<16));
          }
          if (h0seq)  h0seq [(size_t)t*(Bz*Hh) + row*1024 + col] = hi;
          if (outseq) outseq[(size_t)t*(Bz*Hh) + row*1024 + col] = hnew;
          if (t == Tt-1) hn[row*1024 + col] = hnew;
        }
      }
    }
    gbar(bar, &bk);
  }
}

// ---------------- host ----------------

extern "C" void kernel_launch(void* const* d_in, const int* in_sizes, int n_in,
                              void* d_out, int out_size, void* d_ws, size_t ws_size,
                              hipStream_t stream)
{
  (void)in_sizes; (void)n_in; (void)out_size; (void)ws_size;
  const float* X     = (const float*)d_in[0];
  const float* Wxrz0 = (const float*)d_in[1];
  const float* bxrz0 = (const float*)d_in[2];
  const float* Whrz0 = (const float*)d_in[3];
  const float* bhrz0 = (const float*)d_in[4];
  const float* Wxh0  = (const float*)d_in[5];
  const float* bxh0  = (const float*)d_in[6];
  const float* Whh0  = (const float*)d_in[7];
  const float* bhh0  = (const float*)d_in[8];
  const float* Wxrz1 = (const float*)d_in[9];
  const float* bxrz1 = (const float*)d_in[10];
  const float* Whrz1 = (const float*)d_in[11];
  const float* bhrz1 = (const float*)d_in[12];
  const float* Wxh1  = (const float*)d_in[13];
  const float* bxh1  = (const float*)d_in[14];
  const float* Whh1  = (const float*)d_in[15];
  const float* bhh1  = (const float*)d_in[16];

  char* p = (char*)d_ws;
  auto carve = [&](size_t bytes)->char*{
    char* r = p; p += (bytes + 255) & ~(size_t)255; return r;
  };
  unsigned short* Xbf    = (unsigned short*)carve((size_t)Mrows*512*2);
  unsigned short* W0t    = (unsigned short*)carve((size_t)3072*512*2);
  unsigned short* W1t    = (unsigned short*)carve((size_t)3072*1024*2);
  unsigned short* Whrz0t = (unsigned short*)carve((size_t)2048*1024*2);
  unsigned short* Whh0t  = (unsigned short*)carve((size_t)1024*1024*2);
  unsigned short* Whrz1t = (unsigned short*)carve((size_t)2048*1024*2);
  unsigned short* Whh1t  = (unsigned short*)carve((size_t)1024*1024*2);
  float* bias0 = (float*)carve(3072*4);
  float* bias1 = (float*)carve(3072*4);
  unsigned short* XprojRZ = (unsigned short*)carve((size_t)Mrows*2048*2);
  float*          XprojC  = (float*)carve((size_t)Mrows*1024*4);
  unsigned short* H0seq   = (unsigned short*)carve((size_t)Mrows*1024*2);
  unsigned short* hhi  = (unsigned short*)carve(Bz*Hh*2);
  unsigned short* hlo  = (unsigned short*)carve(Bz*Hh*2);
  unsigned short* abhi = (unsigned short*)carve(Bz*Hh*2);
  unsigned short* ablo = (unsigned short*)carve(Bz*Hh*2);
  unsigned* bar = (unsigned*)carve(512);

  hipMemsetAsync(bar, 0, 512, stream);

  k_cvt_bf16<<<2048,256,0,stream>>>(X, Xbf, Mrows*512/4);
  k_transpose_bf16<<<dim3(8,32), 256,0,stream>>>(Wxrz0, W0t, 512, 2048);
  k_transpose_bf16<<<dim3(8,16), 256,0,stream>>>(Wxh0,  W0t + (size_t)2048*512, 512, 1024);
  k_transpose_bf16<<<dim3(16,32),256,0,stream>>>(Whrz0, Whrz0t, 1024, 2048);
  k_transpose_bf16<<<dim3(16,16),256,0,stream>>>(Whh0,  Whh0t, 1024, 1024);
  k_transpose_bf16<<<dim3(16,32),256,0,stream>>>(Wxrz1, W1t, 1024, 2048);
  k_transpose_bf16<<<dim3(16,16),256,0,stream>>>(Wxh1,  W1t + (size_t)2048*1024, 1024, 1024);
  k_transpose_bf16<<<dim3(16,32),256,0,stream>>>(Whrz1, Whrz1t, 1024, 2048);
  k_transpose_bf16<<<dim3(16,16),256,0,stream>>>(Whh1,  Whh1t, 1024, 1024);
  k_bias_fold<<<12,256,0,stream>>>(bxrz0, bhrz0, bxh0, bhh0, bias0);
  k_bias_fold<<<12,256,0,stream>>>(bxrz1, bhrz1, bxh1, bhh1, bias1);

  float* out = (float*)d_out;
  float* hn0 = out + (size_t)Mrows*Hh;
  float* hn1 = hn0 + Bz*Hh;

  // ---- layer 0 ----
  k_xproj_gemm<<<dim3(24,256),256,0,stream>>>(Xbf, W0t, bias0, XprojRZ, XprojC, 512);
  k_gru_layer<<<NBLK,512,0,stream>>>(Whrz0t, Whh0t, XprojRZ, XprojC,
                                     hhi, hlo, abhi, ablo,
                                     H0seq, nullptr, hn0, bar);
  // ---- layer 1 ----
  k_xproj_gemm<<<dim3(24,256),256,0,stream>>>(H0seq, W1t, bias1, XprojRZ, XprojC, 1024);
  k_gru_layer<<<NBLK,512,0,stream>>>(Whrz1t, Whh1t, XprojRZ, XprojC,
                                     hhi, hlo, abhi, ablo,
                                     nullptr, out, hn1, bar + 64);
}